// Round 11
// baseline (835.541 us; speedup 1.0000x reference)
//
#include <hip/hip_runtime.h>
#include <hip/hip_bf16.h>

// adLIF FUSED v4: one kernel, GEMM tile (r6 fp32 FMA k-order VERBATIM ->
// bit-exact) + in-LDS transposed scan per 128-t tile. Wx never touches HBM.
// Ledger: v2 (r19) dispatch 471 / bench 591 (banked best). v3 (r20) = dbuf +
// NONTEMPORAL SCALAR stores -> WRITE_SIZE 131->676 MB (5x write amplification:
// NT bypasses L2 write-combining, 4 B/lane partial-line HBM transactions +
// RMW fetches), VALUBusy 37%, 833 us. RULE: NT only with >=16 B/lane stores.
// v4 = v3 minus NT (plain stores, r19 path) -> SINGLE-VARIABLE dbuf test:
//   dbuf failed twice in the split kernel purely via the 128-VGPR occupancy
//   cliff; here the kernel is GRID-limited (512 blocks = 2/CU, launch_bounds
//   (256,2) caps VGPR at 256) so the objection is void. 1 barrier per 16-k
//   tile; staging overlaps compute across waves. Predict GEMM 421 -> ~370.
//   If dispatch >= 471: dbuf condemned for good, revert to r19 next.
// Block = (b, 128-h strip); LDS 49 KB; scan: 128 threads own one h-column
// each, u/w/s/params in registers for the whole kernel.
// Input dtype (fp32 vs bf16) detected on device from x's bit pattern.

#define M_SZ 65536  // B*T
#define H_SZ 512
#define K_SZ 512
#define B_SZ 128
#define T_SZ 512
#define LSTR 132  // LDS row stride (dwords), %32==4: staging writes conflict-free
#define BUFSZ (16 * LSTR)  // dwords per LDS tile buffer (8448 B)

typedef __attribute__((ext_vector_type(4))) float f32x4;

__device__ __forceinline__ bool detect_bf16(const unsigned int* __restrict__ w) {
  int c = 0;
#pragma unroll
  for (int i = 0; i < 64; ++i) {
    unsigned int e = (w[i] >> 7) & 0xffu;
    c += (e >= 115u && e <= 131u) ? 1 : 0;
  }
  return c > 32;  // bf16 exponents cluster in [115,131]; fp32 mantissa bits don't
}

template <bool ISB>
__device__ __forceinline__ f32x4 ld4t(const void* __restrict__ p, size_t off) {
  if constexpr (!ISB) {
    return *reinterpret_cast<const f32x4*>(reinterpret_cast<const float*>(p) + off);
  } else {
    uint2 v = *reinterpret_cast<const uint2*>(reinterpret_cast<const unsigned short*>(p) + off);
    f32x4 r;
    r.x = __uint_as_float((v.x & 0xffffu) << 16);
    r.y = __uint_as_float(v.x & 0xffff0000u);
    r.z = __uint_as_float((v.y & 0xffffu) << 16);
    r.w = __uint_as_float(v.y & 0xffff0000u);
    return r;
  }
}

template <bool ISB>
__device__ __forceinline__ float ld1t(const void* __restrict__ p, int i) {
  if constexpr (!ISB) return reinterpret_cast<const float*>(p)[i];
  return __uint_as_float((unsigned int)(reinterpret_cast<const unsigned short*>(p)[i]) << 16);
}

// ---------------- fused GEMM + scan body ------------------------------------
template <bool ISB>
__device__ __forceinline__ void fused_body(
    const void* __restrict__ X, const void* __restrict__ Wm,
    const void* __restrict__ alpha_p, const void* __restrict__ beta_p,
    const void* __restrict__ a_p, const void* __restrict__ b_p,
    const void* __restrict__ u0p, const void* __restrict__ w0p,
    const void* __restrict__ s0p, void* __restrict__ out,
    float* __restrict__ As, float* __restrict__ Bs, float* __restrict__ wxs) {
  const int tid = threadIdx.x;
  const int r0 = tid >> 2;       // 0..63: staged row
  const int q0 = (tid & 3) * 4;  // 0,4,8,12: k-group
  const int tx = tid & 15;       // n-group
  const int ty = tid >> 4;       // m-group
  const int b = blockIdx.x >> 2;
  const int N0 = (blockIdx.x & 3) * 128;

  // ---- scan state: REGISTERS, thread tid<128 owns column n=tid (h=N0+tid)
  float al = 0.f, be = 0.f, av = 0.f, bv = 0.f, om = 0.f, u = 0.f, w = 0.f, s = 0.f;
  if (tid < 128) {
    const int h = N0 + tid;
    al = fminf(fmaxf(ld1t<ISB>(alpha_p, h), (float)0.8187307530779818),
               (float)0.9607894391523232);
    be = fminf(fmaxf(ld1t<ISB>(beta_p, h), (float)0.9672161004820059),
               (float)0.9917013044213351);
    av = fminf(fmaxf(ld1t<ISB>(a_p, h), -1.0f), 1.0f);
    bv = fminf(fmaxf(ld1t<ISB>(b_p, h), 0.0f), 2.0f);
    om = __fsub_rn(1.0f, al);
    const int bh = b * H_SZ + h;
    u = ld1t<ISB>(u0p, bh);
    w = ld1t<ISB>(w0p, bh);
    s = ld1t<ISB>(s0p, bh);
  }

  float* outf = reinterpret_cast<float*>(out);
  unsigned short* outu = reinterpret_cast<unsigned short*>(out);

  const size_t boff0 = (size_t)(N0 + r0) * K_SZ + q0;
  const size_t boff1 = (size_t)(N0 + r0 + 64) * K_SZ + q0;

  for (int tt = 0; tt < 4; ++tt) {  // M-tile = 128 consecutive t of batch b
    const size_t M0 = (size_t)b * T_SZ + tt * 128;

    float acc[8][8];
#pragma unroll
    for (int i = 0; i < 8; ++i)
#pragma unroll
      for (int j = 0; j < 8; ++j) acc[i][j] = 0.0f;

    const size_t aoff0 = (M0 + r0) * K_SZ + q0;
    const size_t aoff1 = (M0 + r0 + 64) * K_SZ + q0;

    f32x4 pa0, pa1, pb0, pb1;
    auto prefetch = [&](int kk) {
      pa0 = ld4t<ISB>(X, aoff0 + kk);
      pa1 = ld4t<ISB>(X, aoff1 + kk);
      pb0 = ld4t<ISB>(Wm, boff0 + kk);
      pb1 = ld4t<ISB>(Wm, boff1 + kk);
    };
    auto stage = [&](float* __restrict__ A, float* __restrict__ B) {
      A[(q0 + 0) * LSTR + r0] = pa0.x; A[(q0 + 1) * LSTR + r0] = pa0.y;
      A[(q0 + 2) * LSTR + r0] = pa0.z; A[(q0 + 3) * LSTR + r0] = pa0.w;
      A[(q0 + 0) * LSTR + r0 + 64] = pa1.x; A[(q0 + 1) * LSTR + r0 + 64] = pa1.y;
      A[(q0 + 2) * LSTR + r0 + 64] = pa1.z; A[(q0 + 3) * LSTR + r0 + 64] = pa1.w;
      B[(q0 + 0) * LSTR + r0] = pb0.x; B[(q0 + 1) * LSTR + r0] = pb0.y;
      B[(q0 + 2) * LSTR + r0] = pb0.z; B[(q0 + 3) * LSTR + r0] = pb0.w;
      B[(q0 + 0) * LSTR + r0 + 64] = pb1.x; B[(q0 + 1) * LSTR + r0 + 64] = pb1.y;
      B[(q0 + 2) * LSTR + r0 + 64] = pb1.z; B[(q0 + 3) * LSTR + r0 + 64] = pb1.w;
    };
    auto compute = [&](const float* __restrict__ A, const float* __restrict__ B) {
#pragma unroll
      for (int k = 0; k < 16; ++k) {
        const f32x4 a0 = *reinterpret_cast<const f32x4*>(A + k * LSTR + ty * 4);
        const f32x4 a1 = *reinterpret_cast<const f32x4*>(A + k * LSTR + 64 + ty * 4);
        const f32x4 b0 = *reinterpret_cast<const f32x4*>(B + k * LSTR + tx * 4);
        const f32x4 b1 = *reinterpret_cast<const f32x4*>(B + k * LSTR + 64 + tx * 4);
        const float avv[8] = {a0.x, a0.y, a0.z, a0.w, a1.x, a1.y, a1.z, a1.w};
        const float bvv[8] = {b0.x, b0.y, b0.z, b0.w, b1.x, b1.y, b1.z, b1.w};
#pragma unroll
        for (int i = 0; i < 8; ++i)
#pragma unroll
          for (int j = 0; j < 8; ++j) acc[i][j] += avv[i] * bvv[j];  // contracts to FMA
      }
    };

    // dbuf k-loop: 1 barrier per 16-k tile. Iter i: [barrier: buf(i&1) ready,
    // buf((i+1)&1) free] [stage tile i+1 -> buf((i+1)&1)] [prefetch tile i+2]
    // [compute tile i]. Grid-limited 2 blocks/CU -> VGPR growth is free.
    prefetch(0);
    stage(As, Bs);  // buffer 0 <- tile 0
    prefetch(16);
#pragma clang loop unroll(disable)
    for (int i = 0; i < 32; ++i) {
      __syncthreads();
      const int cb = (i & 1) * BUFSZ;
      const int nb = ((i + 1) & 1) * BUFSZ;
      if (i + 1 < 32) {
        stage(As + nb, Bs + nb);  // overlaps other waves' compute
        if (i + 2 < 32) prefetch(16 * (i + 2));
      }
      compute(As + cb, Bs + cb);
    }
    // acc[r][j] = Wx[t_local = (r<4 ? ty*4+r : 64+ty*4+(r-4))][n = (j<4 ?
    // tx*4+j : 64+tx*4+(j-4))]. Scan in 4 subs of 32 t:
    //   sub0: ty 0..7  rows 0..3 (t 0..31)    sub1: ty 8..15 rows 0..3 (32..63)
    //   sub2: ty 0..7  rows 4..7 (64..95)     sub3: ty 8..15 rows 4..7 (96..127)
#pragma unroll
    for (int sub = 0; sub < 4; ++sub) {
      __syncthreads();  // prior sub's wxs reads (or k-loop compute) complete
      const bool owner = (sub & 1) ? (ty >= 8) : (ty < 8);  // wave-uniform
      if (owner) {
#pragma unroll
        for (int rr = 0; rr < 4; ++rr) {
          const int row = (ty & 7) * 4 + rr;          // t within sub
          const int r = (sub < 2) ? rr : 4 + rr;      // static acc row
          f32x4 v0 = {acc[r][0], acc[r][1], acc[r][2], acc[r][3]};
          f32x4 v1 = {acc[r][4], acc[r][5], acc[r][6], acc[r][7]};
          *reinterpret_cast<f32x4*>(wxs + row * 128 + tx * 4) = v0;
          *reinterpret_cast<f32x4*>(wxs + row * 128 + 64 + tx * 4) = v1;
        }
      }
      __syncthreads();  // wxs[32][128] ready
      if (tid < 128) {  // wave-uniform: waves 0-1 scan, one column per thread
        const size_t tbase =
            ((size_t)b * T_SZ + tt * 128 + sub * 32) * H_SZ + N0 + tid;
#pragma unroll
        for (int t = 0; t < 32; ++t) {
          const float cur = wxs[t * 128 + tid];  // independent of recurrence
          // numpy left-to-right, each op individually rounded (no FMA contraction)
          w = __fadd_rn(__fadd_rn(__fmul_rn(be, w), __fmul_rn(av, u)), __fmul_rn(bv, s));
          u = __fadd_rn(__fmul_rn(al, __fsub_rn(u, s)), __fmul_rn(om, __fsub_rn(cur, w)));
          const bool sp = (u > 1.0f);
          s = sp ? 1.0f : 0.0f;
          // PLAIN stores (r19 path): L2 write-combining merges the 4 B/lane
          // stores into full lines (r20's NT scalar stores -> 5x write ampl.)
          if constexpr (ISB)
            outu[tbase + (size_t)t * H_SZ] = sp ? (unsigned short)0x3F80u : (unsigned short)0u;
          else
            outf[tbase + (size_t)t * H_SZ] = s;
        }
      }
    }
  }
}

__global__ __launch_bounds__(256, 2) void adlif_fused(
    const void* __restrict__ X, const void* __restrict__ Wm,
    const void* __restrict__ alpha_p, const void* __restrict__ beta_p,
    const void* __restrict__ a_p, const void* __restrict__ b_p,
    const void* __restrict__ u0p, const void* __restrict__ w0p,
    const void* __restrict__ s0p, void* __restrict__ out) {
  __shared__ float As[2 * BUFSZ];   // 16.9 KB: double-buffered A tiles
  __shared__ float Bs[2 * BUFSZ];   // 16.9 KB: double-buffered B tiles
  __shared__ float wxs[32 * 128];   // 16 KB: Wx transpose buffer (one 32-t sub)
  if (detect_bf16(reinterpret_cast<const unsigned int*>(X)))
    fused_body<true>(X, Wm, alpha_p, beta_p, a_p, b_p, u0p, w0p, s0p, out, As, Bs, wxs);
  else
    fused_body<false>(X, Wm, alpha_p, beta_p, a_p, b_p, u0p, w0p, s0p, out, As, Bs, wxs);
}

extern "C" void kernel_launch(void* const* d_in, const int* in_sizes, int n_in,
                              void* d_out, int out_size, void* d_ws, size_t ws_size,
                              hipStream_t stream) {
  // single fused dispatch; d_ws unused (Wx never materialized in HBM)
  adlif_fused<<<dim3(B_SZ * 4), dim3(256), 0, stream>>>(
      d_in[0], d_in[1], d_in[2], d_in[3], d_in[4], d_in[5], d_in[6], d_in[7],
      d_in[8], d_out);
}

// Round 12
// 690.653 us; speedup vs baseline: 1.2098x; 1.2098x over previous
//
#include <hip/hip_runtime.h>
#include <hip/hip_bf16.h>

// adLIF FUSED v5: one kernel, GEMM tile (r6 fp32 FMA k-order VERBATIM ->
// bit-exact) + in-LDS transposed scan per 128-t tile. Wx never touches HBM.
// Ledger: v2 (r19) dispatch 471 / bench 591 (banked best, VGPR 124, no dbuf).
// v3/v4 (r20/r21) POST-MORTEM: __launch_bounds__(256,2) capped VGPR at 128
//   while the dbuf body needs ~144 (r15 precedent) -> compiler SPILLED TO
//   SCRATCH in the hot loop. Scratch = global memory: WRITE_SIZE 131->690 MB,
//   FETCH 274->437 MB, VALUBusy 38%, 733 us. NT stores (r20) were irrelevant -
//   r21 reproduced the damage without them. VGPR pinned exactly at the cap
//   was the tell. RULE: never set launch_bounds min-waves below what the body
//   naturally allocates; spill traffic shows up as WRITE/FETCH inflation.
// v5 = v4 with __launch_bounds__(256) (no min-waves): VGPR floats to ~150,
//   no spills. Kernel is GRID-limited at 2 blocks/CU (512 blocks) and
//   2 waves/SIMD only needs VGPR <= 256 -> the allocation is free. This is
//   the clean dbuf test: 1 barrier per 16-k tile, staging overlaps compute.
//   Verdict vs r19's 471 us dispatch: <450 keep; >=471 revert to r19.
// Block = (b, 128-h strip); LDS 49 KB; scan: 128 threads own one h-column
// each, u/w/s/params in registers for the whole kernel.
// Input dtype (fp32 vs bf16) detected on device from x's bit pattern.

#define M_SZ 65536  // B*T
#define H_SZ 512
#define K_SZ 512
#define B_SZ 128
#define T_SZ 512
#define LSTR 132  // LDS row stride (dwords), %32==4: staging writes conflict-free
#define BUFSZ (16 * LSTR)  // dwords per LDS tile buffer (8448 B)

typedef __attribute__((ext_vector_type(4))) float f32x4;

__device__ __forceinline__ bool detect_bf16(const unsigned int* __restrict__ w) {
  int c = 0;
#pragma unroll
  for (int i = 0; i < 64; ++i) {
    unsigned int e = (w[i] >> 7) & 0xffu;
    c += (e >= 115u && e <= 131u) ? 1 : 0;
  }
  return c > 32;  // bf16 exponents cluster in [115,131]; fp32 mantissa bits don't
}

template <bool ISB>
__device__ __forceinline__ f32x4 ld4t(const void* __restrict__ p, size_t off) {
  if constexpr (!ISB) {
    return *reinterpret_cast<const f32x4*>(reinterpret_cast<const float*>(p) + off);
  } else {
    uint2 v = *reinterpret_cast<const uint2*>(reinterpret_cast<const unsigned short*>(p) + off);
    f32x4 r;
    r.x = __uint_as_float((v.x & 0xffffu) << 16);
    r.y = __uint_as_float(v.x & 0xffff0000u);
    r.z = __uint_as_float((v.y & 0xffffu) << 16);
    r.w = __uint_as_float(v.y & 0xffff0000u);
    return r;
  }
}

template <bool ISB>
__device__ __forceinline__ float ld1t(const void* __restrict__ p, int i) {
  if constexpr (!ISB) return reinterpret_cast<const float*>(p)[i];
  return __uint_as_float((unsigned int)(reinterpret_cast<const unsigned short*>(p)[i]) << 16);
}

// ---------------- fused GEMM + scan body ------------------------------------
template <bool ISB>
__device__ __forceinline__ void fused_body(
    const void* __restrict__ X, const void* __restrict__ Wm,
    const void* __restrict__ alpha_p, const void* __restrict__ beta_p,
    const void* __restrict__ a_p, const void* __restrict__ b_p,
    const void* __restrict__ u0p, const void* __restrict__ w0p,
    const void* __restrict__ s0p, void* __restrict__ out,
    float* __restrict__ As, float* __restrict__ Bs, float* __restrict__ wxs) {
  const int tid = threadIdx.x;
  const int r0 = tid >> 2;       // 0..63: staged row
  const int q0 = (tid & 3) * 4;  // 0,4,8,12: k-group
  const int tx = tid & 15;       // n-group
  const int ty = tid >> 4;       // m-group
  const int b = blockIdx.x >> 2;
  const int N0 = (blockIdx.x & 3) * 128;

  // ---- scan state: REGISTERS, thread tid<128 owns column n=tid (h=N0+tid)
  float al = 0.f, be = 0.f, av = 0.f, bv = 0.f, om = 0.f, u = 0.f, w = 0.f, s = 0.f;
  if (tid < 128) {
    const int h = N0 + tid;
    al = fminf(fmaxf(ld1t<ISB>(alpha_p, h), (float)0.8187307530779818),
               (float)0.9607894391523232);
    be = fminf(fmaxf(ld1t<ISB>(beta_p, h), (float)0.9672161004820059),
               (float)0.9917013044213351);
    av = fminf(fmaxf(ld1t<ISB>(a_p, h), -1.0f), 1.0f);
    bv = fminf(fmaxf(ld1t<ISB>(b_p, h), 0.0f), 2.0f);
    om = __fsub_rn(1.0f, al);
    const int bh = b * H_SZ + h;
    u = ld1t<ISB>(u0p, bh);
    w = ld1t<ISB>(w0p, bh);
    s = ld1t<ISB>(s0p, bh);
  }

  float* outf = reinterpret_cast<float*>(out);
  unsigned short* outu = reinterpret_cast<unsigned short*>(out);

  const size_t boff0 = (size_t)(N0 + r0) * K_SZ + q0;
  const size_t boff1 = (size_t)(N0 + r0 + 64) * K_SZ + q0;

  for (int tt = 0; tt < 4; ++tt) {  // M-tile = 128 consecutive t of batch b
    const size_t M0 = (size_t)b * T_SZ + tt * 128;

    float acc[8][8];
#pragma unroll
    for (int i = 0; i < 8; ++i)
#pragma unroll
      for (int j = 0; j < 8; ++j) acc[i][j] = 0.0f;

    const size_t aoff0 = (M0 + r0) * K_SZ + q0;
    const size_t aoff1 = (M0 + r0 + 64) * K_SZ + q0;

    f32x4 pa0, pa1, pb0, pb1;
    auto prefetch = [&](int kk) {
      pa0 = ld4t<ISB>(X, aoff0 + kk);
      pa1 = ld4t<ISB>(X, aoff1 + kk);
      pb0 = ld4t<ISB>(Wm, boff0 + kk);
      pb1 = ld4t<ISB>(Wm, boff1 + kk);
    };
    auto stage = [&](float* __restrict__ A, float* __restrict__ B) {
      A[(q0 + 0) * LSTR + r0] = pa0.x; A[(q0 + 1) * LSTR + r0] = pa0.y;
      A[(q0 + 2) * LSTR + r0] = pa0.z; A[(q0 + 3) * LSTR + r0] = pa0.w;
      A[(q0 + 0) * LSTR + r0 + 64] = pa1.x; A[(q0 + 1) * LSTR + r0 + 64] = pa1.y;
      A[(q0 + 2) * LSTR + r0 + 64] = pa1.z; A[(q0 + 3) * LSTR + r0 + 64] = pa1.w;
      B[(q0 + 0) * LSTR + r0] = pb0.x; B[(q0 + 1) * LSTR + r0] = pb0.y;
      B[(q0 + 2) * LSTR + r0] = pb0.z; B[(q0 + 3) * LSTR + r0] = pb0.w;
      B[(q0 + 0) * LSTR + r0 + 64] = pb1.x; B[(q0 + 1) * LSTR + r0 + 64] = pb1.y;
      B[(q0 + 2) * LSTR + r0 + 64] = pb1.z; B[(q0 + 3) * LSTR + r0 + 64] = pb1.w;
    };
    auto compute = [&](const float* __restrict__ A, const float* __restrict__ B) {
#pragma unroll
      for (int k = 0; k < 16; ++k) {
        const f32x4 a0 = *reinterpret_cast<const f32x4*>(A + k * LSTR + ty * 4);
        const f32x4 a1 = *reinterpret_cast<const f32x4*>(A + k * LSTR + 64 + ty * 4);
        const f32x4 b0 = *reinterpret_cast<const f32x4*>(B + k * LSTR + tx * 4);
        const f32x4 b1 = *reinterpret_cast<const f32x4*>(B + k * LSTR + 64 + tx * 4);
        const float avv[8] = {a0.x, a0.y, a0.z, a0.w, a1.x, a1.y, a1.z, a1.w};
        const float bvv[8] = {b0.x, b0.y, b0.z, b0.w, b1.x, b1.y, b1.z, b1.w};
#pragma unroll
        for (int i = 0; i < 8; ++i)
#pragma unroll
          for (int j = 0; j < 8; ++j) acc[i][j] += avv[i] * bvv[j];  // contracts to FMA
      }
    };

    // dbuf k-loop: 1 barrier per 16-k tile. Iter i: [barrier: buf(i&1) ready,
    // buf((i+1)&1) free] [stage tile i+1 -> buf((i+1)&1)] [prefetch tile i+2]
    // [compute tile i]. Grid-limited 2 blocks/CU -> ~150 VGPR is free.
    prefetch(0);
    stage(As, Bs);  // buffer 0 <- tile 0
    prefetch(16);
#pragma clang loop unroll(disable)
    for (int i = 0; i < 32; ++i) {
      __syncthreads();
      const int cb = (i & 1) * BUFSZ;
      const int nb = ((i + 1) & 1) * BUFSZ;
      if (i + 1 < 32) {
        stage(As + nb, Bs + nb);  // overlaps other waves' compute
        if (i + 2 < 32) prefetch(16 * (i + 2));
      }
      compute(As + cb, Bs + cb);
    }
    // acc[r][j] = Wx[t_local = (r<4 ? ty*4+r : 64+ty*4+(r-4))][n = (j<4 ?
    // tx*4+j : 64+tx*4+(j-4))]. Scan in 4 subs of 32 t:
    //   sub0: ty 0..7  rows 0..3 (t 0..31)    sub1: ty 8..15 rows 0..3 (32..63)
    //   sub2: ty 0..7  rows 4..7 (64..95)     sub3: ty 8..15 rows 4..7 (96..127)
#pragma unroll
    for (int sub = 0; sub < 4; ++sub) {
      __syncthreads();  // prior sub's wxs reads (or k-loop compute) complete
      const bool owner = (sub & 1) ? (ty >= 8) : (ty < 8);  // wave-uniform
      if (owner) {
#pragma unroll
        for (int rr = 0; rr < 4; ++rr) {
          const int row = (ty & 7) * 4 + rr;          // t within sub
          const int r = (sub < 2) ? rr : 4 + rr;      // static acc row
          f32x4 v0 = {acc[r][0], acc[r][1], acc[r][2], acc[r][3]};
          f32x4 v1 = {acc[r][4], acc[r][5], acc[r][6], acc[r][7]};
          *reinterpret_cast<f32x4*>(wxs + row * 128 + tx * 4) = v0;
          *reinterpret_cast<f32x4*>(wxs + row * 128 + 64 + tx * 4) = v1;
        }
      }
      __syncthreads();  // wxs[32][128] ready
      if (tid < 128) {  // wave-uniform: waves 0-1 scan, one column per thread
        const size_t tbase =
            ((size_t)b * T_SZ + tt * 128 + sub * 32) * H_SZ + N0 + tid;
#pragma unroll
        for (int t = 0; t < 32; ++t) {
          const float cur = wxs[t * 128 + tid];  // independent of recurrence
          // numpy left-to-right, each op individually rounded (no FMA contraction)
          w = __fadd_rn(__fadd_rn(__fmul_rn(be, w), __fmul_rn(av, u)), __fmul_rn(bv, s));
          u = __fadd_rn(__fmul_rn(al, __fsub_rn(u, s)), __fmul_rn(om, __fsub_rn(cur, w)));
          const bool sp = (u > 1.0f);
          s = sp ? 1.0f : 0.0f;
          // plain stores: wave-coalesced 256 B contiguous -> L2 write-combined
          if constexpr (ISB)
            outu[tbase + (size_t)t * H_SZ] = sp ? (unsigned short)0x3F80u : (unsigned short)0u;
          else
            outf[tbase + (size_t)t * H_SZ] = s;
        }
      }
    }
  }
}

__global__ __launch_bounds__(256) void adlif_fused(
    const void* __restrict__ X, const void* __restrict__ Wm,
    const void* __restrict__ alpha_p, const void* __restrict__ beta_p,
    const void* __restrict__ a_p, const void* __restrict__ b_p,
    const void* __restrict__ u0p, const void* __restrict__ w0p,
    const void* __restrict__ s0p, void* __restrict__ out) {
  __shared__ float As[2 * BUFSZ];   // 16.9 KB: double-buffered A tiles
  __shared__ float Bs[2 * BUFSZ];   // 16.9 KB: double-buffered B tiles
  __shared__ float wxs[32 * 128];   // 16 KB: Wx transpose buffer (one 32-t sub)
  if (detect_bf16(reinterpret_cast<const unsigned int*>(X)))
    fused_body<true>(X, Wm, alpha_p, beta_p, a_p, b_p, u0p, w0p, s0p, out, As, Bs, wxs);
  else
    fused_body<false>(X, Wm, alpha_p, beta_p, a_p, b_p, u0p, w0p, s0p, out, As, Bs, wxs);
}

extern "C" void kernel_launch(void* const* d_in, const int* in_sizes, int n_in,
                              void* d_out, int out_size, void* d_ws, size_t ws_size,
                              hipStream_t stream) {
  // single fused dispatch; d_ws unused (Wx never materialized in HBM)
  adlif_fused<<<dim3(B_SZ * 4), dim3(256), 0, stream>>>(
      d_in[0], d_in[1], d_in[2], d_in[3], d_in[4], d_in[5], d_in[6], d_in[7],
      d_in[8], d_out);
}

// Round 13
// 593.417 us; speedup vs baseline: 1.4080x; 1.1639x over previous
//
#include <hip/hip_runtime.h>
#include <hip/hip_bf16.h>

// adLIF FUSED v6 = r19 (banked best: dispatch 471 / bench 591, VGPR 124)
// + XCD-aware block swizzle. One kernel: GEMM tile (r6 fp32 FMA k-order
// VERBATIM -> bit-exact) + in-LDS transposed scan per 128-t tile; Wx never
// touches HBM.
// CLOSED ARCS (do not revisit):
//  - dbuf GEMM: condemned 3x (r11 VGPR200/620us, r15 144/555, r22 164/610 +
//    occupancy collapse 18.7->11.4%). RULE: VGPR <= 128 always; the 2-barrier
//    single-buffer k-loop is the GEMM.
//  - launch_bounds min-waves: (256,2) forced VGPR cap 128 under a ~150-VGPR
//    body -> scratch spills -> WRITE 131->690 MB (r20/r21). Never cap below
//    natural allocation.
//  - NT scalar stores: 5x write amplification (r20). NT only for >=16 B/lane.
//  - standalone scan kernel: latency-bound floor ~140 us (r0-r17), fused
//    transposed scan costs ~50 us -> fusion stands.
// v6 swizzle: blockIdx round-robins XCDs (id%8); old id=b*4+strip put the 4
// strips of b (which share 1 MB of X rows) on 4 DIFFERENT XCDs -> X fetched
// ~2x (FETCH 274 vs 135 ideal). New map puts ids {c,c+8,c+16,c+24} = the 4
// strips of one b on ONE XCD: b=(id>>5)*8+(id&7), strip=(id>>3)&3. Predict
// FETCH -> 150-200 MB, prefetch L2-hits shrink the staging-barrier stall ->
// dispatch 440-470, bench 545-590. Falsifier: FETCH unchanged -> id%8
// round-robin assumption wrong -> revert swizzle (r19 is the plateau).
// Input dtype (fp32 vs bf16) detected on device from x's bit pattern.

#define M_SZ 65536  // B*T
#define H_SZ 512
#define K_SZ 512
#define B_SZ 128
#define T_SZ 512
#define LSTR 132  // LDS row stride (dwords), %32==4: staging writes conflict-free

typedef __attribute__((ext_vector_type(4))) float f32x4;

__device__ __forceinline__ bool detect_bf16(const unsigned int* __restrict__ w) {
  int c = 0;
#pragma unroll
  for (int i = 0; i < 64; ++i) {
    unsigned int e = (w[i] >> 7) & 0xffu;
    c += (e >= 115u && e <= 131u) ? 1 : 0;
  }
  return c > 32;  // bf16 exponents cluster in [115,131]; fp32 mantissa bits don't
}

template <bool ISB>
__device__ __forceinline__ f32x4 ld4t(const void* __restrict__ p, size_t off) {
  if constexpr (!ISB) {
    return *reinterpret_cast<const f32x4*>(reinterpret_cast<const float*>(p) + off);
  } else {
    uint2 v = *reinterpret_cast<const uint2*>(reinterpret_cast<const unsigned short*>(p) + off);
    f32x4 r;
    r.x = __uint_as_float((v.x & 0xffffu) << 16);
    r.y = __uint_as_float(v.x & 0xffff0000u);
    r.z = __uint_as_float((v.y & 0xffffu) << 16);
    r.w = __uint_as_float(v.y & 0xffff0000u);
    return r;
  }
}

template <bool ISB>
__device__ __forceinline__ float ld1t(const void* __restrict__ p, int i) {
  if constexpr (!ISB) return reinterpret_cast<const float*>(p)[i];
  return __uint_as_float((unsigned int)(reinterpret_cast<const unsigned short*>(p)[i]) << 16);
}

// ---------------- fused GEMM + scan body ------------------------------------
template <bool ISB>
__device__ __forceinline__ void fused_body(
    const void* __restrict__ X, const void* __restrict__ Wm,
    const void* __restrict__ alpha_p, const void* __restrict__ beta_p,
    const void* __restrict__ a_p, const void* __restrict__ b_p,
    const void* __restrict__ u0p, const void* __restrict__ w0p,
    const void* __restrict__ s0p, void* __restrict__ out,
    float* __restrict__ As, float* __restrict__ Bs, float* __restrict__ wxs) {
  const int tid = threadIdx.x;
  const int r0 = tid >> 2;       // 0..63: staged row
  const int q0 = (tid & 3) * 4;  // 0,4,8,12: k-group
  const int tx = tid & 15;       // n-group
  const int ty = tid >> 4;       // m-group
  // XCD swizzle: strips {0..3} of batch b -> ids {c, c+8, c+16, c+24} (one XCD
  // under id%8 round-robin). Bijective over 512. Per-block work identical.
  const int id = blockIdx.x;
  const int b = ((id >> 5) << 3) + (id & 7);
  const int N0 = ((id >> 3) & 3) * 128;

  // ---- scan state: REGISTERS, thread tid<128 owns column n=tid (h=N0+tid)
  float al = 0.f, be = 0.f, av = 0.f, bv = 0.f, om = 0.f, u = 0.f, w = 0.f, s = 0.f;
  if (tid < 128) {
    const int h = N0 + tid;
    al = fminf(fmaxf(ld1t<ISB>(alpha_p, h), (float)0.8187307530779818),
               (float)0.9607894391523232);
    be = fminf(fmaxf(ld1t<ISB>(beta_p, h), (float)0.9672161004820059),
               (float)0.9917013044213351);
    av = fminf(fmaxf(ld1t<ISB>(a_p, h), -1.0f), 1.0f);
    bv = fminf(fmaxf(ld1t<ISB>(b_p, h), 0.0f), 2.0f);
    om = __fsub_rn(1.0f, al);
    const int bh = b * H_SZ + h;
    u = ld1t<ISB>(u0p, bh);
    w = ld1t<ISB>(w0p, bh);
    s = ld1t<ISB>(s0p, bh);
  }

  float* outf = reinterpret_cast<float*>(out);
  unsigned short* outu = reinterpret_cast<unsigned short*>(out);

  const size_t boff0 = (size_t)(N0 + r0) * K_SZ + q0;
  const size_t boff1 = (size_t)(N0 + r0 + 64) * K_SZ + q0;

  for (int tt = 0; tt < 4; ++tt) {  // M-tile = 128 consecutive t of batch b
    const size_t M0 = (size_t)b * T_SZ + tt * 128;

    float acc[8][8];
#pragma unroll
    for (int i = 0; i < 8; ++i)
#pragma unroll
      for (int j = 0; j < 8; ++j) acc[i][j] = 0.0f;

    const size_t aoff0 = (M0 + r0) * K_SZ + q0;
    const size_t aoff1 = (M0 + r0 + 64) * K_SZ + q0;

    f32x4 pa0 = ld4t<ISB>(X, aoff0), pa1 = ld4t<ISB>(X, aoff1);
    f32x4 pb0 = ld4t<ISB>(Wm, boff0), pb1 = ld4t<ISB>(Wm, boff1);

    for (int kk = 0; kk < K_SZ; kk += 16) {  // r6 k-loop VERBATIM (2 barriers)
      __syncthreads();  // prior compute done -> LDS free
      As[(q0 + 0) * LSTR + r0] = pa0.x; As[(q0 + 1) * LSTR + r0] = pa0.y;
      As[(q0 + 2) * LSTR + r0] = pa0.z; As[(q0 + 3) * LSTR + r0] = pa0.w;
      As[(q0 + 0) * LSTR + r0 + 64] = pa1.x; As[(q0 + 1) * LSTR + r0 + 64] = pa1.y;
      As[(q0 + 2) * LSTR + r0 + 64] = pa1.z; As[(q0 + 3) * LSTR + r0 + 64] = pa1.w;
      Bs[(q0 + 0) * LSTR + r0] = pb0.x; Bs[(q0 + 1) * LSTR + r0] = pb0.y;
      Bs[(q0 + 2) * LSTR + r0] = pb0.z; Bs[(q0 + 3) * LSTR + r0] = pb0.w;
      Bs[(q0 + 0) * LSTR + r0 + 64] = pb1.x; Bs[(q0 + 1) * LSTR + r0 + 64] = pb1.y;
      Bs[(q0 + 2) * LSTR + r0 + 64] = pb1.z; Bs[(q0 + 3) * LSTR + r0 + 64] = pb1.w;
      __syncthreads();  // tile ready
      if (kk + 16 < K_SZ) {  // prefetch next chunk (L2-hit after swizzle)
        pa0 = ld4t<ISB>(X, aoff0 + kk + 16); pa1 = ld4t<ISB>(X, aoff1 + kk + 16);
        pb0 = ld4t<ISB>(Wm, boff0 + kk + 16); pb1 = ld4t<ISB>(Wm, boff1 + kk + 16);
      }
#pragma unroll
      for (int k = 0; k < 16; ++k) {
        const f32x4 a0 = *reinterpret_cast<const f32x4*>(As + k * LSTR + ty * 4);
        const f32x4 a1 = *reinterpret_cast<const f32x4*>(As + k * LSTR + 64 + ty * 4);
        const f32x4 b0 = *reinterpret_cast<const f32x4*>(Bs + k * LSTR + tx * 4);
        const f32x4 b1 = *reinterpret_cast<const f32x4*>(Bs + k * LSTR + 64 + tx * 4);
        const float avv[8] = {a0.x, a0.y, a0.z, a0.w, a1.x, a1.y, a1.z, a1.w};
        const float bvv[8] = {b0.x, b0.y, b0.z, b0.w, b1.x, b1.y, b1.z, b1.w};
#pragma unroll
        for (int i = 0; i < 8; ++i)
#pragma unroll
          for (int j = 0; j < 8; ++j) acc[i][j] += avv[i] * bvv[j];  // contracts to FMA
      }
    }
    // acc[r][j] = Wx[t_local = (r<4 ? ty*4+r : 64+ty*4+(r-4))][n = (j<4 ?
    // tx*4+j : 64+tx*4+(j-4))]. Scan in 4 subs of 32 t:
    //   sub0: ty 0..7  rows 0..3 (t 0..31)    sub1: ty 8..15 rows 0..3 (32..63)
    //   sub2: ty 0..7  rows 4..7 (64..95)     sub3: ty 8..15 rows 4..7 (96..127)
#pragma unroll
    for (int sub = 0; sub < 4; ++sub) {
      __syncthreads();  // prior sub's wxs reads (or k-loop compute) complete
      const bool owner = (sub & 1) ? (ty >= 8) : (ty < 8);  // wave-uniform
      if (owner) {
#pragma unroll
        for (int rr = 0; rr < 4; ++rr) {
          const int row = (ty & 7) * 4 + rr;          // t within sub
          const int r = (sub < 2) ? rr : 4 + rr;      // static acc row
          f32x4 v0 = {acc[r][0], acc[r][1], acc[r][2], acc[r][3]};
          f32x4 v1 = {acc[r][4], acc[r][5], acc[r][6], acc[r][7]};
          *reinterpret_cast<f32x4*>(wxs + row * 128 + tx * 4) = v0;
          *reinterpret_cast<f32x4*>(wxs + row * 128 + 64 + tx * 4) = v1;
        }
      }
      __syncthreads();  // wxs[32][128] ready
      if (tid < 128) {  // wave-uniform: waves 0-1 scan, one column per thread
        const size_t tbase =
            ((size_t)b * T_SZ + tt * 128 + sub * 32) * H_SZ + N0 + tid;
#pragma unroll
        for (int t = 0; t < 32; ++t) {
          const float cur = wxs[t * 128 + tid];  // independent of recurrence
          // numpy left-to-right, each op individually rounded (no FMA contraction)
          w = __fadd_rn(__fadd_rn(__fmul_rn(be, w), __fmul_rn(av, u)), __fmul_rn(bv, s));
          u = __fadd_rn(__fmul_rn(al, __fsub_rn(u, s)), __fmul_rn(om, __fsub_rn(cur, w)));
          const bool sp = (u > 1.0f);
          s = sp ? 1.0f : 0.0f;
          // plain stores: wave-coalesced 256 B contiguous -> L2 write-combined
          if constexpr (ISB)
            outu[tbase + (size_t)t * H_SZ] = sp ? (unsigned short)0x3F80u : (unsigned short)0u;
          else
            outf[tbase + (size_t)t * H_SZ] = s;
        }
      }
    }
  }
}

__global__ __launch_bounds__(256) void adlif_fused(
    const void* __restrict__ X, const void* __restrict__ Wm,
    const void* __restrict__ alpha_p, const void* __restrict__ beta_p,
    const void* __restrict__ a_p, const void* __restrict__ b_p,
    const void* __restrict__ u0p, const void* __restrict__ w0p,
    const void* __restrict__ s0p, void* __restrict__ out) {
  __shared__ float As[16 * LSTR];   // 8.45 KB GEMM staging (single buffer)
  __shared__ float Bs[16 * LSTR];   // 8.45 KB
  __shared__ float wxs[32 * 128];   // 16 KB Wx transpose buffer (one 32-t sub)
  if (detect_bf16(reinterpret_cast<const unsigned int*>(X)))
    fused_body<true>(X, Wm, alpha_p, beta_p, a_p, b_p, u0p, w0p, s0p, out, As, Bs, wxs);
  else
    fused_body<false>(X, Wm, alpha_p, beta_p, a_p, b_p, u0p, w0p, s0p, out, As, Bs, wxs);
}

extern "C" void kernel_launch(void* const* d_in, const int* in_sizes, int n_in,
                              void* d_out, int out_size, void* d_ws, size_t ws_size,
                              hipStream_t stream) {
  // single fused dispatch; d_ws unused (Wx never materialized in HBM)
  adlif_fused<<<dim3(B_SZ * 4), dim3(256), 0, stream>>>(
      d_in[0], d_in[1], d_in[2], d_in[3], d_in[4], d_in[5], d_in[6], d_in[7],
      d_in[8], d_out);
}